// Round 17
// baseline (132.110 us; speedup 1.0000x reference)
//
#include <hip/hip_runtime.h>

#define NB 32
#define LL 2048
#define CH 512
#define BQ 512
#define HH 1024

typedef __attribute__((ext_vector_type(8))) short bf16x8;
typedef __attribute__((ext_vector_type(16))) float f32x16;

__device__ __forceinline__ unsigned int cvt_pk_bf16(float a, float b) {
  unsigned int r;
  asm("v_cvt_pk_bf16_f32 %0, %1, %2" : "=v"(r) : "v"(a), "v"(b));
  return r;   // lo16 = bf16(a), hi16 = bf16(b)
}

__device__ __forceinline__ float fast_tanh(float x) {
  float e = __builtin_amdgcn_exp2f(x * 2.885390081777927f);
  return 1.0f - 2.0f * __builtin_amdgcn_rcpf(e + 1.0f);
}

// ================ fused small prep ================
// [0,256)   : pack Wc -> wcbp (B-frag order, 65536 uint4)
// [256,384) : res_qc = query@Wq^T + bc (32768)
// [384,400) : zero logit (65536 f32)
// 400       : zero out (16384 f32)
__global__ __launch_bounds__(256) void k_prep(const float* __restrict__ Wc,
                                              uint4* __restrict__ wcbp,
                                              const float* __restrict__ query,
                                              const float* __restrict__ Wq,
                                              const float* __restrict__ bc,
                                              float* __restrict__ resqc,
                                              float* __restrict__ logit,
                                              float* __restrict__ out) {
  int bid = blockIdx.x, t = threadIdx.x;
  if (bid < 256) {
    int gid = bid * 256 + t;   // 65536 = 32 cg * 32 ks * 64 lanes
    int lane = gid & 63, ks = (gid >> 6) & 31, cg = gid >> 11;
    int lo = lane & 31, hi = lane >> 5;
    const float4* s = (const float4*)(Wc + (size_t)(cg * 32 + lo) * CH + hi * 8 + ks * 16);
    float4 v0 = s[0], v1 = s[1];
    uint4 p;
    p.x = cvt_pk_bf16(v0.x, v0.y);
    p.y = cvt_pk_bf16(v0.z, v0.w);
    p.z = cvt_pk_bf16(v1.x, v1.y);
    p.w = cvt_pk_bf16(v1.z, v1.w);
    wcbp[gid] = p;
  } else if (bid < 384) {
    int gid = (bid - 256) * 256 + t;   // 32768
    int b = gid >> 10, h = gid & 1023;
    const float4* q4 = (const float4*)(query + (size_t)b * BQ);
    const float4* w4 = (const float4*)(Wq + (size_t)h * BQ);
    float acc = 0.f;
#pragma unroll 4
    for (int i = 0; i < BQ / 4; ++i) {
      float4 a = q4[i], w = w4[i];
      acc += a.x * w.x + a.y * w.y + a.z * w.z + a.w * w.w;
    }
    resqc[gid] = acc + bc[h];
  } else if (bid < 400) {
    float4* p = (float4*)logit + (bid - 384) * 1024 + t;
#pragma unroll
    for (int i = 0; i < 4; ++i) p[i * 256] = (float4){0, 0, 0, 0};
  } else {
    float4* p = (float4*)out + t;
#pragma unroll
    for (int i = 0; i < 16; ++i) p[i * 256] = (float4){0, 0, 0, 0};
  }
}

// ---------------- main: one 64-row tile per block, A in LDS, 2 blocks/CU ----
// 2048 blocks = 32 b x 32 rowtiles x 2 N-halves; 512 thr (8 waves). Wave =
// 64r x 64c, acc[2][2]=64 AGPR. A: [64][520] bf16 LDS. B: packed wcbp, saddr
// loads. kg=0 B-frags prefetched into regs BEFORE staging+barrier (hides the
// post-barrier B latency under the staging phase). Epilogue operands hoisted.
__global__ __launch_bounds__(512, 4) void k_logits_f(const float* __restrict__ ctx,
                                                     const uint4* __restrict__ bpk,
                                                     const float* __restrict__ resqc,
                                                     const float* __restrict__ Wo,
                                                     float* __restrict__ logit) {
  __shared__ unsigned short A[64 * 520];   // 66560 B

  const int t = threadIdx.x;
  const int bid = blockIdx.x;
  // XCD pair-swizzle: both N-halves of one A-tile land adjacent on one XCD
  const int swz = (bid & 7) * 256 + (bid >> 3);
  const int lt = swz >> 1, nh = swz & 1;
  const int b = lt >> 5, row0 = (lt & 31) << 6;

  const int wv = t >> 6, lane = t & 63;
  const int lo = lane & 31, hi = lane >> 5;

  // wave-uniform B base -> saddr loads; fixed per-lane voffset
  const int wvu = __builtin_amdgcn_readfirstlane(wv);
  const char* b0 = (const char*)(bpk + (size_t)((nh * 16 + wvu * 2) * 32) * 64);
  const char* b1 = b0 + 32768;
  const unsigned vo = lane * 16;

  // hoisted epilogue operands (independent; waited on at first use)
  const int c0 = nh * 512 + wv * 64;
  const float q0 = resqc[b * HH + c0 + lo], q1 = resqc[b * HH + c0 + 32 + lo];
  const float w0 = Wo[c0 + lo],             w1 = Wo[c0 + 32 + lo];

  // prefetch kg=0 B fragments (overlap with staging below)
  bf16x8 pb0[4], pb1[4];
#pragma unroll
  for (int j = 0; j < 4; ++j) {
    pb0[j] = *(const bf16x8*)(b0 + vo + j * 1024);
    pb1[j] = *(const bf16x8*)(b1 + vo + j * 1024);
  }

  // stage A tile: 64 rows x 512 f32 -> bf16 LDS (strength-reduced addressing)
  {
    const int r0 = t >> 7, c4 = t & 127;
    const float4* src = (const float4*)(ctx + ((size_t)(b * LL + row0)) * CH) + (size_t)r0 * 128 + c4;
    unsigned short* dst = A + r0 * 520 + c4 * 4;
#pragma unroll
    for (int i = 0; i < 16; ++i) {
      float4 v = src[(size_t)i * 512];     // +4 rows
      uint2 w;
      w.x = cvt_pk_bf16(v.x, v.y);
      w.y = cvt_pk_bf16(v.z, v.w);
      *(uint2*)(dst + i * (4 * 520)) = w;
    }
  }
  __syncthreads();

  const char* a0 = (const char*)A + lo * 1040 + hi * 16;   // rows lo / lo+32

  f32x16 acc[2][2];
#pragma unroll
  for (int m = 0; m < 2; ++m)
#pragma unroll
    for (int n = 0; n < 2; ++n) acc[m][n] = (f32x16){0,0,0,0,0,0,0,0,0,0,0,0,0,0,0,0};

  // ---- kg = 0: B from prefetched registers ----
#pragma unroll
  for (int j = 0; j < 4; ++j) {
    bf16x8 fa0 = *(const bf16x8*)(a0 + j * 32);
    bf16x8 fa1 = *(const bf16x8*)(a0 + 33280 + j * 32);
    __builtin_amdgcn_s_setprio(1);
    acc[0][0] = __builtin_amdgcn_mfma_f32_32x32x16_bf16(fa0, pb0[j], acc[0][0], 0, 0, 0);
    acc[0][1] = __builtin_amdgcn_mfma_f32_32x32x16_bf16(fa0, pb1[j], acc[0][1], 0, 0, 0);
    acc[1][0] = __builtin_amdgcn_mfma_f32_32x32x16_bf16(fa1, pb0[j], acc[1][0], 0, 0, 0);
    acc[1][1] = __builtin_amdgcn_mfma_f32_32x32x16_bf16(fa1, pb1[j], acc[1][1], 0, 0, 0);
    __builtin_amdgcn_s_setprio(0);
  }
  b0 += 4096; b1 += 4096;

  // ---- kg = 1..7 ----
#pragma unroll 2
  for (int kg = 1; kg < 8; ++kg) {
#pragma unroll
    for (int j = 0; j < 4; ++j) {
      bf16x8 fb0 = *(const bf16x8*)(b0 + vo + j * 1024);
      bf16x8 fb1 = *(const bf16x8*)(b1 + vo + j * 1024);
      bf16x8 fa0 = *(const bf16x8*)(a0 + kg * 128 + j * 32);
      bf16x8 fa1 = *(const bf16x8*)(a0 + 33280 + kg * 128 + j * 32);
      __builtin_amdgcn_s_setprio(1);
      acc[0][0] = __builtin_amdgcn_mfma_f32_32x32x16_bf16(fa0, fb0, acc[0][0], 0, 0, 0);
      acc[0][1] = __builtin_amdgcn_mfma_f32_32x32x16_bf16(fa0, fb1, acc[0][1], 0, 0, 0);
      acc[1][0] = __builtin_amdgcn_mfma_f32_32x32x16_bf16(fa1, fb0, acc[1][0], 0, 0, 0);
      acc[1][1] = __builtin_amdgcn_mfma_f32_32x32x16_bf16(fa1, fb1, acc[1][1], 0, 0, 0);
      __builtin_amdgcn_s_setprio(0);
    }
    b0 += 4096; b1 += 4096;   // uniform SALU bumps
  }

  // epilogue: tanh + Wo-weighted col-sum -> transpose-reduce -> global atomics
  float v[32];
#pragma unroll
  for (int m = 0; m < 2; ++m)
#pragma unroll
    for (int r = 0; r < 16; ++r)
      v[m * 16 + r] = w0 * fast_tanh(acc[m][0][r] + q0)
                    + w1 * fast_tanh(acc[m][1][r] + q1);
  // transpose-reduce over 32 col-lanes: lane lo ends with the full sum of value lo
#pragma unroll
  for (int sdist = 16; sdist >= 1; sdist >>= 1) {
#pragma unroll
    for (int i = 0; i < sdist; ++i) {
      float a = v[i], c = v[i + sdist];
      float keep = (lo & sdist) ? c : a;
      float send = (lo & sdist) ? a : c;
      v[i] = keep + __shfl_xor(send, sdist, 64);
    }
  }
  int rr = lo & 15;
  int row_local = (lo >> 4) * 32 + (rr & 3) + 8 * (rr >> 2) + 4 * hi;  // C/D row map
  atomicAdd(&logit[(size_t)b * LL + row0 + row_local], v[0]);
}

// ---------------- weights: mask*exp(logit+bo), normalize over L ----------------
__global__ __launch_bounds__(256) void k_weights(const float* __restrict__ mask,
                                                 const float* __restrict__ bo,
                                                 const float* __restrict__ logit,
                                                 float* __restrict__ wout) {
  __shared__ float red[4];
  int b = blockIdx.x, t = threadIdx.x;
  float bov = bo[0];
  float w[8];
  float s = 0.f;
#pragma unroll
  for (int i = 0; i < 8; ++i) {
    int l = t + 256 * i;
    float e = mask[b * LL + l] * __expf(logit[b * LL + l] + bov);
    w[i] = e; s += e;
  }
#pragma unroll
  for (int m = 32; m >= 1; m >>= 1) s += __shfl_xor(s, m, 64);
  int wave = t >> 6, lane = t & 63;
  if (lane == 0) red[wave] = s;
  __syncthreads();
  float inv = 1.0f / (red[0] + red[1] + red[2] + red[3] + 1e-5f);
#pragma unroll
  for (int i = 0; i < 8; ++i) wout[b * LL + t + 256 * i] = w[i] * inv;
}

// ---------------- output[b][c] = sum_l weights[b][l] * ctx[b][l][c] (ctx in L3) ----
// float4 per thread: c4 = t&127, row-phase rh = t>>7 (2 threads cover 128 l's).
__global__ __launch_bounds__(256) void k_output_f32(const float* __restrict__ ctx,
                                                    const float* __restrict__ weights,
                                                    float* __restrict__ out) {
  __shared__ float wl[128];
  int bid = blockIdx.x;            // 512 = 32 b * 16 chunks
  int b = bid >> 4, chunk = bid & 15;
  int t = threadIdx.x;
  int l0 = chunk * 128;
  if (t < 128) wl[t] = weights[b * LL + l0 + t];
  __syncthreads();
  int c4 = t & 127, rh = t >> 7;
  const float4* cp = (const float4*)(ctx + ((size_t)(b * LL + l0)) * CH) + c4;
  float4 a4 = {0, 0, 0, 0};
#pragma unroll 4
  for (int l = rh; l < 128; l += 2) {
    float w = wl[l];
    float4 vv = cp[(size_t)l * 128];
    a4.x += w * vv.x; a4.y += w * vv.y; a4.z += w * vv.z; a4.w += w * vv.w;
  }
  atomicAdd(&out[b * CH + c4 * 4 + 0], a4.x);
  atomicAdd(&out[b * CH + c4 * 4 + 1], a4.y);
  atomicAdd(&out[b * CH + c4 * 4 + 2], a4.z);
  atomicAdd(&out[b * CH + c4 * 4 + 3], a4.w);
}

extern "C" void kernel_launch(void* const* d_in, const int* in_sizes, int n_in,
                              void* d_out, int out_size, void* d_ws, size_t ws_size,
                              hipStream_t stream) {
  const float* query = (const float*)d_in[0];
  const float* ctx   = (const float*)d_in[1];
  const float* mask  = (const float*)d_in[2];
  const float* Wq    = (const float*)d_in[3];
  const float* Wc    = (const float*)d_in[4];
  const float* bc    = (const float*)d_in[5];
  const float* Wo    = (const float*)d_in[6];
  const float* bo    = (const float*)d_in[7];
  float* out = (float*)d_out;

  uint4* wcbp  = (uint4*)d_ws;                                    // 1 MB packed bf16 Wc
  float* resqc = (float*)((char*)d_ws + (1 << 20));               // 128 KB
  float* logit = (float*)((char*)d_ws + (1 << 20) + (1 << 17));   // 256 KB
  float* wout = out + NB * CH;                                    // final weights slot

  k_prep<<<401, 256, 0, stream>>>(Wc, wcbp, query, Wq, bc, resqc, logit, out);
  k_logits_f<<<2048, 512, 0, stream>>>(ctx, wcbp, resqc, Wo, logit);
  k_weights<<<32, 256, 0, stream>>>(mask, bo, logit, wout);
  k_output_f32<<<512, 256, 0, stream>>>(ctx, wout, out);
}

// Round 18
// 129.286 us; speedup vs baseline: 1.0218x; 1.0218x over previous
//
#include <hip/hip_runtime.h>

#define NB 32
#define LL 2048
#define CH 512
#define BQ 512
#define HH 1024

typedef __attribute__((ext_vector_type(8))) short bf16x8;
typedef __attribute__((ext_vector_type(16))) float f32x16;

__device__ __forceinline__ unsigned int cvt_pk_bf16(float a, float b) {
  unsigned int r;
  asm("v_cvt_pk_bf16_f32 %0, %1, %2" : "=v"(r) : "v"(a), "v"(b));
  return r;   // lo16 = bf16(a), hi16 = bf16(b)
}

__device__ __forceinline__ float fast_tanh(float x) {
  float e = __builtin_amdgcn_exp2f(x * 2.885390081777927f);
  return 1.0f - 2.0f * __builtin_amdgcn_rcpf(e + 1.0f);
}

// ================ fused small prep ================
// [0,256)   : pack Wc -> wcbp (B-frag order, 65536 uint4)
// [256,384) : res_qc = query@Wq^T + bc (32768)
// [384,400) : zero logit (65536 f32)
// 400       : zero out (16384 f32)
__global__ __launch_bounds__(256) void k_prep(const float* __restrict__ Wc,
                                              uint4* __restrict__ wcbp,
                                              const float* __restrict__ query,
                                              const float* __restrict__ Wq,
                                              const float* __restrict__ bc,
                                              float* __restrict__ resqc,
                                              float* __restrict__ logit,
                                              float* __restrict__ out) {
  int bid = blockIdx.x, t = threadIdx.x;
  if (bid < 256) {
    int gid = bid * 256 + t;   // 65536 = 32 cg * 32 ks * 64 lanes
    int lane = gid & 63, ks = (gid >> 6) & 31, cg = gid >> 11;
    int lo = lane & 31, hi = lane >> 5;
    const float4* s = (const float4*)(Wc + (size_t)(cg * 32 + lo) * CH + hi * 8 + ks * 16);
    float4 v0 = s[0], v1 = s[1];
    uint4 p;
    p.x = cvt_pk_bf16(v0.x, v0.y);
    p.y = cvt_pk_bf16(v0.z, v0.w);
    p.z = cvt_pk_bf16(v1.x, v1.y);
    p.w = cvt_pk_bf16(v1.z, v1.w);
    wcbp[gid] = p;
  } else if (bid < 384) {
    int gid = (bid - 256) * 256 + t;   // 32768
    int b = gid >> 10, h = gid & 1023;
    const float4* q4 = (const float4*)(query + (size_t)b * BQ);
    const float4* w4 = (const float4*)(Wq + (size_t)h * BQ);
    float acc = 0.f;
#pragma unroll 4
    for (int i = 0; i < BQ / 4; ++i) {
      float4 a = q4[i], w = w4[i];
      acc += a.x * w.x + a.y * w.y + a.z * w.z + a.w * w.w;
    }
    resqc[gid] = acc + bc[h];
  } else if (bid < 400) {
    float4* p = (float4*)logit + (bid - 384) * 1024 + t;
#pragma unroll
    for (int i = 0; i < 4; ++i) p[i * 256] = (float4){0, 0, 0, 0};
  } else {
    float4* p = (float4*)out + t;
#pragma unroll
    for (int i = 0; i < 16; ++i) p[i * 256] = (float4){0, 0, 0, 0};
  }
}

// ---------------- main: one 64-row tile per block, A in LDS, 2 blocks/CU ----
// (exact r13 configuration -- measured best: 111 us, total 125.6)
// 2048 blocks = 32 b x 32 rowtiles x 2 N-halves; 512 thr (8 waves). Wave =
// 64r x 64c, acc[2][2]=64 AGPR. A: [64][520] bf16 LDS (0 conflicts measured).
// B: packed wcbp via wave-uniform saddr loads.
__global__ __launch_bounds__(512, 4) void k_logits_f(const float* __restrict__ ctx,
                                                     const uint4* __restrict__ bpk,
                                                     const float* __restrict__ resqc,
                                                     const float* __restrict__ Wo,
                                                     float* __restrict__ logit) {
  __shared__ unsigned short A[64 * 520];   // 66560 B

  const int t = threadIdx.x;
  const int bid = blockIdx.x;
  // XCD pair-swizzle: both N-halves of one A-tile land adjacent on one XCD
  const int swz = (bid & 7) * 256 + (bid >> 3);
  const int lt = swz >> 1, nh = swz & 1;
  const int b = lt >> 5, row0 = (lt & 31) << 6;

  // stage A tile: 64 rows x 512 f32 -> bf16 LDS (coalesced; 16 float4/thread)
  {
    const float4* src = (const float4*)(ctx + ((size_t)(b * LL + row0)) * CH);
#pragma unroll
    for (int i = 0; i < 16; ++i) {
      int f = i * 512 + t;
      int r = f >> 7, c4 = f & 127;
      float4 v = src[f];
      uint2 w;
      w.x = cvt_pk_bf16(v.x, v.y);
      w.y = cvt_pk_bf16(v.z, v.w);
      *(uint2*)(A + r * 520 + c4 * 4) = w;
    }
  }
  __syncthreads();

  const int wv = t >> 6, lane = t & 63;
  const int lo = lane & 31, hi = lane >> 5;

  // wave-uniform B base -> saddr loads; fixed per-lane voffset
  const int wvu = __builtin_amdgcn_readfirstlane(wv);
  const char* b0 = (const char*)(bpk + (size_t)((nh * 16 + wvu * 2) * 32) * 64);
  const char* b1 = b0 + 32768;
  const unsigned vo = lane * 16;

  const char* a0 = (const char*)A + lo * 1040 + hi * 16;   // rows lo / lo+32

  f32x16 acc[2][2];
#pragma unroll
  for (int m = 0; m < 2; ++m)
#pragma unroll
    for (int n = 0; n < 2; ++n) acc[m][n] = (f32x16){0,0,0,0,0,0,0,0,0,0,0,0,0,0,0,0};

  for (int kg = 0; kg < 8; ++kg) {   // 8 groups x 4 ks
#pragma unroll
    for (int j = 0; j < 4; ++j) {
      uint4 ub0 = *(const uint4*)(b0 + vo + j * 1024);
      uint4 ub1 = *(const uint4*)(b1 + vo + j * 1024);
      bf16x8 fa0 = *(const bf16x8*)(a0 + kg * 128 + j * 32);
      bf16x8 fa1 = *(const bf16x8*)(a0 + 33280 + kg * 128 + j * 32);
      bf16x8 fb0, fb1;
      __builtin_memcpy(&fb0, &ub0, 16);
      __builtin_memcpy(&fb1, &ub1, 16);
      acc[0][0] = __builtin_amdgcn_mfma_f32_32x32x16_bf16(fa0, fb0, acc[0][0], 0, 0, 0);
      acc[0][1] = __builtin_amdgcn_mfma_f32_32x32x16_bf16(fa0, fb1, acc[0][1], 0, 0, 0);
      acc[1][0] = __builtin_amdgcn_mfma_f32_32x32x16_bf16(fa1, fb0, acc[1][0], 0, 0, 0);
      acc[1][1] = __builtin_amdgcn_mfma_f32_32x32x16_bf16(fa1, fb1, acc[1][1], 0, 0, 0);
    }
    b0 += 4096; b1 += 4096;   // uniform SALU bumps
  }

  // epilogue: tanh + Wo-weighted col-sum -> transpose-reduce -> global atomics
  const int c0 = nh * 512 + wv * 64;
  float q0 = resqc[b * HH + c0 + lo], q1 = resqc[b * HH + c0 + 32 + lo];
  float w0 = Wo[c0 + lo],             w1 = Wo[c0 + 32 + lo];
  float v[32];
#pragma unroll
  for (int m = 0; m < 2; ++m)
#pragma unroll
    for (int r = 0; r < 16; ++r)
      v[m * 16 + r] = w0 * fast_tanh(acc[m][0][r] + q0)
                    + w1 * fast_tanh(acc[m][1][r] + q1);
  // transpose-reduce over 32 col-lanes: lane lo ends with the full sum of value lo
#pragma unroll
  for (int sdist = 16; sdist >= 1; sdist >>= 1) {
#pragma unroll
    for (int i = 0; i < sdist; ++i) {
      float a = v[i], c = v[i + sdist];
      float keep = (lo & sdist) ? c : a;
      float send = (lo & sdist) ? a : c;
      v[i] = keep + __shfl_xor(send, sdist, 64);
    }
  }
  int rr = lo & 15;
  int row_local = (lo >> 4) * 32 + (rr & 3) + 8 * (rr >> 2) + 4 * hi;  // C/D row map
  atomicAdd(&logit[(size_t)b * LL + row0 + row_local], v[0]);
}

// ---------------- weights: mask*exp(logit+bo), normalize over L ----------------
__global__ __launch_bounds__(256) void k_weights(const float* __restrict__ mask,
                                                 const float* __restrict__ bo,
                                                 const float* __restrict__ logit,
                                                 float* __restrict__ wout) {
  __shared__ float red[4];
  int b = blockIdx.x, t = threadIdx.x;
  float bov = bo[0];
  float w[8];
  float s = 0.f;
#pragma unroll
  for (int i = 0; i < 8; ++i) {
    int l = t + 256 * i;
    float e = mask[b * LL + l] * __expf(logit[b * LL + l] + bov);
    w[i] = e; s += e;
  }
#pragma unroll
  for (int m = 32; m >= 1; m >>= 1) s += __shfl_xor(s, m, 64);
  int wave = t >> 6, lane = t & 63;
  if (lane == 0) red[wave] = s;
  __syncthreads();
  float inv = 1.0f / (red[0] + red[1] + red[2] + red[3] + 1e-5f);
#pragma unroll
  for (int i = 0; i < 8; ++i) wout[b * LL + t + 256 * i] = w[i] * inv;
}

// ---------------- output[b][c] = sum_l weights[b][l] * ctx[b][l][c] (ctx in L3) ----
// float4 per thread: c4 = t&127, row-phase rh = t>>7 (2 threads cover 128 l's).
__global__ __launch_bounds__(256) void k_output_f32(const float* __restrict__ ctx,
                                                    const float* __restrict__ weights,
                                                    float* __restrict__ out) {
  __shared__ float wl[128];
  int bid = blockIdx.x;            // 512 = 32 b * 16 chunks
  int b = bid >> 4, chunk = bid & 15;
  int t = threadIdx.x;
  int l0 = chunk * 128;
  if (t < 128) wl[t] = weights[b * LL + l0 + t];
  __syncthreads();
  int c4 = t & 127, rh = t >> 7;
  const float4* cp = (const float4*)(ctx + ((size_t)(b * LL + l0)) * CH) + c4;
  float4 a4 = {0, 0, 0, 0};
#pragma unroll 4
  for (int l = rh; l < 128; l += 2) {
    float w = wl[l];
    float4 vv = cp[(size_t)l * 128];
    a4.x += w * vv.x; a4.y += w * vv.y; a4.z += w * vv.z; a4.w += w * vv.w;
  }
  atomicAdd(&out[b * CH + c4 * 4 + 0], a4.x);
  atomicAdd(&out[b * CH + c4 * 4 + 1], a4.y);
  atomicAdd(&out[b * CH + c4 * 4 + 2], a4.z);
  atomicAdd(&out[b * CH + c4 * 4 + 3], a4.w);
}

extern "C" void kernel_launch(void* const* d_in, const int* in_sizes, int n_in,
                              void* d_out, int out_size, void* d_ws, size_t ws_size,
                              hipStream_t stream) {
  const float* query = (const float*)d_in[0];
  const float* ctx   = (const float*)d_in[1];
  const float* mask  = (const float*)d_in[2];
  const float* Wq    = (const float*)d_in[3];
  const float* Wc    = (const float*)d_in[4];
  const float* bc    = (const float*)d_in[5];
  const float* Wo    = (const float*)d_in[6];
  const float* bo    = (const float*)d_in[7];
  float* out = (float*)d_out;

  uint4* wcbp  = (uint4*)d_ws;                                    // 1 MB packed bf16 Wc
  float* resqc = (float*)((char*)d_ws + (1 << 20));               // 128 KB
  float* logit = (float*)((char*)d_ws + (1 << 20) + (1 << 17));   // 256 KB
  float* wout = out + NB * CH;                                    // final weights slot

  k_prep<<<401, 256, 0, stream>>>(Wc, wcbp, query, Wq, bc, resqc, logit, out);
  k_logits_f<<<2048, 512, 0, stream>>>(ctx, wcbp, resqc, Wo, logit);
  k_weights<<<32, 256, 0, stream>>>(mask, bo, logit, wout);
  k_output_f32<<<512, 256, 0, stream>>>(ctx, wout, out);
}